// Round 17
// baseline (105.272 us; speedup 1.0000x reference)
//
#include <hip/hip_runtime.h>
#include <cstdint>

typedef float f32x4 __attribute__((ext_vector_type(4)));
typedef unsigned short u16;

#define NROWS 4096
#define DIM 512
#define ZROWS 8192
#define DIMP 128     /* projected dims (Walsh coefficients 0..127) */
#define NTILES 64    /* 8192/128 */
#define NBLOCKS 2080 /* 64*65/2 upper-triangular 128x128 tile pairs */
#define GRID3 1040   /* 2080/2 — 2 tiles/block, 4 blocks/CU resident */
#define THR 100.0f   /* fp8 certify: d_hat>=100 => d_true>=(10-2)^2=64 => sum<3e-7 */

// ---------------- kernel 1: FWHT + fp8-e4m3 quantize, fragment-ordered Qf8 -------
// Exact Sylvester WHT over 512 (3 in-lane + 6 shfl stages); rows of H/sqrt(512)
// orthonormal => Parseval: d_proj <= d_true. Coefs quantized to OCP fp8 e4m3
// (halves the filter's L2 operand traffic vs bf16; same MFMA rate). Qf8 layout:
// byte(row,c,kg,j) = (row>>4)*2048 + c*512 + kg*128 + (row&15)*8 + j, so filter
// lane L reads 8B at blk*2048 + c*512 + L*8 — fully coalesced 512B wave-loads.
// Also resets the last-block ticket each replay (d_ws not re-poisoned).
__global__ __launch_bounds__(256) void prep_kernel(const float* __restrict__ lbl,
                                                   const float* __restrict__ pred,
                                                   unsigned char* __restrict__ Qf8,
                                                   float* __restrict__ xnorm,
                                                   float* __restrict__ pnorm,
                                                   unsigned* __restrict__ ticket) {
    if (blockIdx.x == 0 && threadIdx.x == 0) *ticket = 0u;
    const int w = threadIdx.x >> 6;
    const int l = threadIdx.x & 63;
    const int row = blockIdx.x * 4 + w;
    const float* src = (row < NROWS) ? (lbl + (size_t)row * DIM)
                                     : (pred + (size_t)(row - NROWS) * DIM);
    const float4 v0 = *(const float4*)(src + l * 8);
    const float4 v1 = *(const float4*)(src + l * 8 + 4);
    float h[8] = {v0.x, v0.y, v0.z, v0.w, v1.x, v1.y, v1.z, v1.w};

    float nrm = 0.f;  // exact f32 norm of the ORIGINAL row (fallback uses it)
#pragma unroll
    for (int j = 0; j < 8; ++j) nrm += h[j] * h[j];
#pragma unroll
    for (int off = 32; off; off >>= 1) nrm += __shfl_xor(nrm, off);
    if (l == 0) xnorm[row] = nrm;

#define BFLY(a, b) { float t = h[a]; h[a] = t + h[b]; h[b] = t - h[b]; }
    BFLY(0, 1) BFLY(2, 3) BFLY(4, 5) BFLY(6, 7)
    BFLY(0, 2) BFLY(1, 3) BFLY(4, 6) BFLY(5, 7)
    BFLY(0, 4) BFLY(1, 5) BFLY(2, 6) BFLY(3, 7)
#undef BFLY
#pragma unroll
    for (int m = 1; m <= 32; m <<= 1) {
#pragma unroll
        for (int j = 0; j < 8; ++j) {
            float p = __shfl_xor(h[j], m);
            h[j] = (l & m) ? (p - h[j]) : (h[j] + p);
        }
    }
    // scale by 1/sqrt(512), pack 8 coefs -> 2x4 fp8 bytes; pnorm from DEQUANTIZED
#pragma unroll
    for (int j = 0; j < 8; ++j) h[j] *= 0.04419417382f;
    uint32_t lo = 0, hi = 0;
    lo = __builtin_amdgcn_cvt_pk_fp8_f32(h[0], h[1], lo, false);
    lo = __builtin_amdgcn_cvt_pk_fp8_f32(h[2], h[3], lo, true);
    hi = __builtin_amdgcn_cvt_pk_fp8_f32(h[4], h[5], hi, false);
    hi = __builtin_amdgcn_cvt_pk_fp8_f32(h[6], h[7], hi, true);
    // dequant for pnorm — selector must be a LITERAL (frontend constraint)
    float s = 0.f, b0, b1;
    b0 = __builtin_amdgcn_cvt_f32_fp8(lo, 0); b1 = __builtin_amdgcn_cvt_f32_fp8(hi, 0);
    s += b0 * b0 + b1 * b1;
    b0 = __builtin_amdgcn_cvt_f32_fp8(lo, 1); b1 = __builtin_amdgcn_cvt_f32_fp8(hi, 1);
    s += b0 * b0 + b1 * b1;
    b0 = __builtin_amdgcn_cvt_f32_fp8(lo, 2); b1 = __builtin_amdgcn_cvt_f32_fp8(hi, 2);
    s += b0 * b0 + b1 * b1;
    b0 = __builtin_amdgcn_cvt_f32_fp8(lo, 3); b1 = __builtin_amdgcn_cvt_f32_fp8(hi, 3);
    s += b0 * b0 + b1 * b1;
    if (l < 16) {
        // lane l holds k=8l..8l+7: chunk=l>>2, kgroup=l&3
        const size_t off8 = (size_t)(row >> 4) * 2048 + (l >> 2) * 512 + (l & 3) * 128 + (row & 15) * 8;
        *(uint2*)(Qf8 + off8) = make_uint2(lo, hi);
    }
    s = (l < 16) ? s : 0.f;
#pragma unroll
    for (int off = 32; off; off >>= 1) s += __shfl_xor(s, off);
    if (l == 0) pnorm[row] = s;
}

// ---------------- kernel 2: fp8 register-MFMA certify filter + fused reduce ------
// r15 structure (2 tiles/block, cross-tile prefetch, no LDS/barriers) with fp8
// fragments (8B/lane loads — half the bytes/lines of bf16) and the final
// reduction fused in via ticket + deterministic index-ordered last-block sum.
__global__ __launch_bounds__(256) void mmd_filter_kernel(const unsigned char* __restrict__ Qf8,
                                                         const float* __restrict__ pnorm,
                                                         const float* __restrict__ lbl,
                                                         const float* __restrict__ pred,
                                                         const float* __restrict__ xnorm,
                                                         float* __restrict__ partials,
                                                         unsigned* __restrict__ ticket,
                                                         float* __restrict__ out) {
    __shared__ float red[4];
    __shared__ unsigned isLast;

    const int bid0 = (int)blockIdx.x;
    const int phys = (bid0 & 7) * (GRID3 / 8) + (bid0 >> 3);  // XCD-contiguous
    const int tid = threadIdx.x;
    const int wv = tid >> 6;
    const int l = tid & 63;
    const int wm = wv >> 1, wn = wv & 1;
    const int rl = l & 15;

    int bm = 0, rem = phys * 2;  // block handles triangle ids 2*phys, 2*phys+1
    while (rem >= NTILES - bm) { rem -= NTILES - bm; ++bm; }

    auto baseof = [&](int rowblk) {
        return (const char*)Qf8 + (size_t)(rowblk >> 4) * 2048 + (size_t)l * 8;
    };

    f32x4 acc[4][4];
#pragma unroll
    for (int m = 0; m < 4; ++m)
#pragma unroll
        for (int n = 0; n < 4; ++n) acc[m][n] = (f32x4){0.f, 0.f, 0.f, 0.f};

    long aE[4], bE[4], aO[4], bO[4];
    const char* bA = baseof(bm * 128 + wm * 64);
    const char* bB = baseof((bm + rem) * 128 + wn * 64);

#define LDX(a, b, kc, pA, pB)                                       \
    {                                                               \
        _Pragma("unroll") for (int m = 0; m < 4; ++m) {             \
            a[m] = *(const long*)((pA) + m * 2048 + (kc) * 512);    \
            b[m] = *(const long*)((pB) + m * 2048 + (kc) * 512);    \
        }                                                           \
    }
#define MMX(a, b)                                                   \
    {                                                               \
        _Pragma("unroll") for (int m = 0; m < 4; ++m)               \
            _Pragma("unroll") for (int n = 0; n < 4; ++n)           \
                acc[m][n] = __builtin_amdgcn_mfma_f32_16x16x32_fp8_fp8(a[m], b[n], acc[m][n], 0, 0, 0); \
    }

    LDX(aE, bE, 0, bA, bB);
    float grand = 0.f;

#pragma unroll 1
    for (int k = 0; k < 2; ++k) {
        const int bn = bm + rem;
        const int rowA = bm * 128 + wm * 64;
        const int rowB = bn * 128 + wn * 64;

        LDX(aO, bO, 1, bA, bB); MMX(aE, bE);
        LDX(aE, bE, 2, bA, bB); MMX(aO, bO);
        LDX(aO, bO, 3, bA, bB); MMX(aE, bE);

        int bm2 = bm, rem2 = rem + 1;  // next tile; prefetch chunk 0 into even regs
        if (rem2 >= NTILES - bm2) { rem2 = 0; ++bm2; }
        if (k < 1) {
            bA = baseof(bm2 * 128 + wm * 64);
            bB = baseof((bm2 + rem2) * 128 + wn * 64);
            LDX(aE, bE, 0, bA, bB);
        }
        MMX(aO, bO);

        // ---- epilogue (register-only; certify-skip + rare exact fallback) ----
        float pj[4];
        float4 piv[4];
#pragma unroll
        for (int n = 0; n < 4; ++n) pj[n] = pnorm[rowB + n * 16 + rl];
#pragma unroll
        for (int m = 0; m < 4; ++m)
            piv[m] = *(const float4*)(pnorm + rowA + m * 16 + (l >> 4) * 4);

        float tmin = 1e30f;  // min fragment distance (i==j excluded)
#pragma unroll
        for (int m = 0; m < 4; ++m)
#pragma unroll
            for (int n = 0; n < 4; ++n) {
                const int i0 = rowA + m * 16 + (l >> 4) * 4;
                const int j = rowB + n * 16 + rl;
                const int delta = j - i0;
                float d0 = (piv[m].x + pj[n]) - 2.f * acc[m][n][0];
                float d1 = (piv[m].y + pj[n]) - 2.f * acc[m][n][1];
                float d2 = (piv[m].z + pj[n]) - 2.f * acc[m][n][2];
                float d3 = (piv[m].w + pj[n]) - 2.f * acc[m][n][3];
                d0 = (delta == 0) ? 1e30f : d0;
                d1 = (delta == 1) ? 1e30f : d1;
                d2 = (delta == 2) ? 1e30f : d2;
                d3 = (delta == 3) ? 1e30f : d3;
                tmin = fminf(tmin, fminf(fminf(d0, d1), fminf(d2, d3)));
            }

        if (__ballot(tmin < THR)) {  // rare (~9 pairs expected); wave-uniform
            float local = 0.f;
#pragma unroll
            for (int m = 0; m < 4; ++m)
#pragma unroll
                for (int n = 0; n < 4; ++n) {
                    float d[4];
                    d[0] = (piv[m].x + pj[n]) - 2.f * acc[m][n][0];
                    d[1] = (piv[m].y + pj[n]) - 2.f * acc[m][n][1];
                    d[2] = (piv[m].z + pj[n]) - 2.f * acc[m][n][2];
                    d[3] = (piv[m].w + pj[n]) - 2.f * acc[m][n][3];
                    const int i0 = rowA + m * 16 + (l >> 4) * 4;
                    const int j = rowB + n * 16 + rl;
#pragma unroll
                    for (int r = 0; r < 4; ++r) {
                        unsigned long long bal = __ballot((d[r] < THR) && (i0 + r != j));
                        while (bal) {  // wave-cooperative exact f32 term
                            const int src = __ffsll((long long)bal) - 1;
                            bal &= bal - 1;
                            const int ii = __shfl(i0 + r, src);
                            const int jj = __shfl(j, src);
                            const float* ri = (ii < NROWS) ? lbl + (size_t)ii * DIM
                                                           : pred + (size_t)(ii - NROWS) * DIM;
                            const float* rj = (jj < NROWS) ? lbl + (size_t)jj * DIM
                                                           : pred + (size_t)(jj - NROWS) * DIM;
                            const float4 a0 = *(const float4*)(ri + l * 8);
                            const float4 a1 = *(const float4*)(ri + l * 8 + 4);
                            const float4 c0 = *(const float4*)(rj + l * 8);
                            const float4 c1 = *(const float4*)(rj + l * 8 + 4);
                            float p = a0.x * c0.x + a0.y * c0.y + a0.z * c0.z + a0.w * c0.w +
                                      a1.x * c1.x + a1.y * c1.y + a1.z * c1.z + a1.w * c1.w;
#pragma unroll
                            for (int off = 32; off; off >>= 1) p += __shfl_xor(p, off);
                            if (l == src) {
                                float dt = xnorm[ii] + xnorm[jj] - 2.f * p;
                                local += exp2f(-0.72134752f * dt);
                            }
                        }
                    }
                }
            const float sgn = ((bm < 32) == (bn < 32)) ? 1.f : -1.f;
            grand += local * sgn * ((bm == bn) ? 1.f : 2.f);
        }
#pragma unroll
        for (int m = 0; m < 4; ++m)
#pragma unroll
            for (int n = 0; n < 4; ++n) acc[m][n] = (f32x4){0.f, 0.f, 0.f, 0.f};
        bm = bm2; rem = rem2;
    }
#undef LDX
#undef MMX

    // ---- block reduce -> partials[phys] (agent scope: read cross-XCD later) ----
#pragma unroll
    for (int off = 32; off; off >>= 1) grand += __shfl_xor(grand, off);
    if (l == 0) red[wv] = grand;
    __syncthreads();
    if (tid == 0)
        __hip_atomic_store(partials + phys, red[0] + red[1] + red[2] + red[3],
                           __ATOMIC_RELAXED, __HIP_MEMORY_SCOPE_AGENT);

    // ---- fused final reduce: last block sums partials in INDEX order ------------
    __threadfence();
    if (tid == 0) isLast = (atomicAdd(ticket, 1u) == GRID3 - 1) ? 1u : 0u;
    __syncthreads();
    if (isLast) {
        __threadfence();
        float s = 0.f;
        for (int i = tid; i < GRID3; i += 256)
            s += __hip_atomic_load(partials + i, __ATOMIC_RELAXED, __HIP_MEMORY_SCOPE_AGENT);
#pragma unroll
        for (int off = 32; off; off >>= 1) s += __shfl_xor(s, off);
        if (l == 0) red[wv] = s;
        __syncthreads();
        if (tid == 0)  // + 8192 = Z-diagonal (exp(0)=1, sign +1, exact)
            out[0] = (red[0] + red[1] + red[2] + red[3] + 8192.f) * (1.f / 16777216.f);
    }
}

extern "C" void kernel_launch(void* const* d_in, const int* in_sizes, int n_in,
                              void* d_out, int out_size, void* d_ws, size_t ws_size,
                              hipStream_t stream) {
    const float* lbl = (const float*)d_in[0];
    const float* pred = (const float*)d_in[1];
    unsigned char* Qf8 = (unsigned char*)d_ws;                        // 1 MiB
    float* xnorm = (float*)((char*)d_ws + (size_t)ZROWS * DIMP);      // 32 KiB
    float* pnorm = xnorm + ZROWS;                                     // 32 KiB
    float* partials = pnorm + ZROWS;                                  // 4.2 KiB
    unsigned* ticket = (unsigned*)(partials + GRID3);                 // 4 B

    prep_kernel<<<ZROWS / 4, 256, 0, stream>>>(lbl, pred, Qf8, xnorm, pnorm, ticket);
    mmd_filter_kernel<<<GRID3, 256, 0, stream>>>(Qf8, pnorm, lbl, pred, xnorm,
                                                 partials, ticket, (float*)d_out);
}